// Round 1
// baseline (333.188 us; speedup 1.0000x reference)
//
#include <hip/hip_runtime.h>
#include <hip/hip_bf16.h>
#include <stdint.h>

// MultiHeadAttentionNoScale: B=2, L=2048, D=1024, H=16, dk=64.
// R7: attn occupancy fix — in-block KV split. Block = 256 threads (4 waves):
//     wave pair {0,1} handles KV tiles 0..31, pair {2,3} handles 32..63, each
//     pair with its own K/V LDS buffers (KV tile 32 rows). Partial O and
//     row-sum R combined exactly (addition) through LDS at the end. 2048 ->
//     4096 waves (8 -> 16 waves/CU). LDS stays 25.6KB (4 blocks/CU by grid).
//     P-store stride 72 -> 36: conflict-free ds_write_b16 / ds_read_b128.
//     Keeps proven semantics: rmb scalar mask, ones-MFMA row sums,
//     single-buffered 2-barrier K/V staging, exp2 with log2e folded into Q.

typedef __bf16 bf16;
typedef __bf16 bf16x8 __attribute__((ext_vector_type(8)));
typedef float f32x4 __attribute__((ext_vector_type(4)));

#define AS1 __attribute__((address_space(1)))
#define AS3 __attribute__((address_space(3)))

__device__ __forceinline__ void g2l16(const void* g, void* l) {
    // async global->LDS, 16B per lane; LDS dest = wave-uniform base + lane*16
    __builtin_amdgcn_global_load_lds((AS1 void*)g, (AS3 void*)l, 16, 0, 0);
}

// true iff this lane's bit is set in wave-uniform mask m
__device__ __forceinline__ bool lane_masked(unsigned long long m) {
#if __has_builtin(__builtin_amdgcn_inverse_ballot_w64)
    return __builtin_amdgcn_inverse_ballot_w64(m);
#else
    return (m >> (threadIdx.x & 63)) & 1ull;
#endif
}

#define LOG2E 1.44269504088896f

// ---------------- fp32 -> bf16 convert (3 tensors, one launch) ----------------
__global__ __launch_bounds__(256) void cvt3_kernel(const float* __restrict__ a0,
                                                   const float* __restrict__ a1,
                                                   const float* __restrict__ a2,
                                                   bf16* o0, bf16* o1, bf16* o2) {
    int y = blockIdx.y;
    const float* in = (y == 0) ? a0 : (y == 1) ? a1 : a2;
    bf16* out = (y == 0) ? o0 : (y == 1) ? o1 : o2;
    int idx = blockIdx.x * 256 + threadIdx.x;
    float4 v = ((const float4*)in)[idx];
    __align__(8) bf16 o[4];
    o[0] = (bf16)v.x; o[1] = (bf16)v.y; o[2] = (bf16)v.z; o[3] = (bf16)v.w;
    *(uint2*)(out + (size_t)idx * 4) = *(const uint2*)o;
}

// ---------------- mask representation detect (int32 / uint8 / fp32) ----------------
__global__ __launch_bounds__(256) void mdetect_kernel(const unsigned int* __restrict__ w,
                                                      int* __restrict__ flag) {
    int idx = blockIdx.x * 256 + threadIdx.x;
    unsigned v = w[idx];
    int f = 0;
    if (v == 0x3F800000u) f = 2;        // float 1.0 pattern -> fp32 mask
    else if (v > 1u) f = 1;             // bytes packed -> uint8 mask
    unsigned long long b1 = __ballot(f & 1);
    unsigned long long b2 = __ballot(f & 2);
    if ((threadIdx.x & 63) == 0) {
        int agg = (b1 ? 1 : 0) | (b2 ? 2 : 0);
        if (agg) atomicOr(flag, agg);
    }
}

// ---------------- mask -> bitmask mb[row][kword], bit=1 means masked ----------------
__global__ __launch_bounds__(256) void mpack_kernel(const void* __restrict__ mask,
                                                    unsigned long long* __restrict__ mb,
                                                    const int* __restrict__ flag) {
    int idx = blockIdx.x * 256 + threadIdx.x;
    int f = *flag;
    bool v;
    if (f & 2)      v = ((const float*)mask)[idx] != 0.0f;
    else if (f & 1) v = ((const unsigned char*)mask)[idx] != 0;
    else            v = ((const int*)mask)[idx] != 0;
    unsigned long long b = __ballot(v);
    if ((threadIdx.x & 63) == 0) mb[idx >> 6] = b;
}

// ---------------- mb -> rmb: lane-bit layout for attn's C-fragment ----------------
// word(task=qg*32+kt, r, nt): bit(lane) = mask[qg*16 + (lane>>4)*4 + r][kt*64 + nt*16 + (lane&15)]
__global__ __launch_bounds__(256) void rpack_kernel(const unsigned long long* __restrict__ mb,
                                                    unsigned long long* __restrict__ rmb) {
    int task = blockIdx.x * 4 + (threadIdx.x >> 6);   // 0..4095
    int qg = task >> 5, kt = task & 31;
    int lane = threadIdx.x & 63, quad = lane >> 4, col = lane & 15;
    #pragma unroll
    for (int r = 0; r < 4; ++r) {
        unsigned long long wrow = mb[(size_t)(qg * 16 + quad * 4 + r) * 32 + kt];
        #pragma unroll
        for (int nt = 0; nt < 4; ++nt) {
            unsigned long long b = __ballot(((wrow >> (nt * 16 + col)) & 1ull) != 0);
            if (lane == 0) rmb[(size_t)task * 16 + r * 4 + nt] = b;
        }
    }
}

// ---------------- W [k][n] fp32 -> Wt [n][k] bf16 (64x64 LDS tile transpose) ----------------
__global__ __launch_bounds__(256) void wtrans_kernel(const float* W0, const float* W1,
                                                     const float* W2, const float* W3,
                                                     bf16* T0, bf16* T1, bf16* T2, bf16* T3) {
    const float* W; bf16* T;
    int y = blockIdx.y;
    if (y == 0)      { W = W0; T = T0; }
    else if (y == 1) { W = W1; T = T1; }
    else if (y == 2) { W = W2; T = T2; }
    else             { W = W3; T = T3; }
    int tx = blockIdx.x & 15, ty = blockIdx.x >> 4;
    int n0 = tx * 64, k0 = ty * 64;
    __shared__ __align__(16) bf16 t[64 * 72];   // [k][n], +8 pad
    int tid = threadIdx.x;
    #pragma unroll
    for (int rr = 0; rr < 4; ++rr) {
        int idx = rr * 256 + tid;
        int r = idx >> 4, c4 = (idx & 15) * 4;
        float4 v = *(const float4*)(W + (size_t)(k0 + r) * 1024 + n0 + c4);
        __align__(8) bf16 o[4];
        o[0] = (bf16)v.x; o[1] = (bf16)v.y; o[2] = (bf16)v.z; o[3] = (bf16)v.w;
        *(uint2*)&t[r * 72 + c4] = *(const uint2*)o;
    }
    __syncthreads();
    #pragma unroll
    for (int rr = 0; rr < 2; ++rr) {
        int idx = rr * 256 + tid;
        int n = idx >> 3, kc = (idx & 7) * 8;
        __align__(16) bf16 o[8];
        #pragma unroll
        for (int j = 0; j < 8; ++j) o[j] = t[(kc + j) * 72 + n];
        *(uint4*)(T + (size_t)(n0 + n) * 1024 + k0 + kc) = *(const uint4*)o;
    }
}

// ---------------- 128x128 bt-GEMM core ----------------
// C[m,n] = (sum_k A[m,k]*Bt[n,k] + bias[n]) * scale
// MODE 0: bf16 head-layout [b][h][l][dk]; MODE 2: bf16 V^T [b][h][dk][l]
template <int MODE>
__device__ __forceinline__ void gemm128_core(const bf16* __restrict__ A,
                                             const bf16* __restrict__ Bt,
                                             const float* __restrict__ bias,
                                             void* __restrict__ Out, int bm, int bn,
                                             float scale) {
    __shared__ __align__(16) bf16 la[128 * 32];
    __shared__ __align__(16) bf16 lb[128 * 32];
    int tid = threadIdx.x;
    int w = tid >> 6, lane = tid & 63;
    int quad = lane >> 4, col = lane & 15;
    int wm = w >> 1, wn = w & 1;
    int m0 = bm * 128, n0 = bn * 128;
    f32x4 acc[4][4];
    f32x4 z = {0.f, 0.f, 0.f, 0.f};
    #pragma unroll
    for (int i = 0; i < 4; ++i)
        #pragma unroll
        for (int j = 0; j < 4; ++j) acc[i][j] = z;
    int srow = lane >> 2;
    int skc = (lane & 3) * 8;
    for (int kt = 0; kt < 32; ++kt) {
        int kk = kt * 32;
        __syncthreads();
        #pragma unroll
        for (int rr = 0; rr < 2; ++rr) {
            int ch = rr * 4 + w;
            int row = ch * 16 + srow;
            g2l16(A + (size_t)(m0 + row) * 1024 + kk + skc, &la[ch * 512]);
            g2l16(Bt + (size_t)(n0 + row) * 1024 + kk + skc, &lb[ch * 512]);
        }
        __syncthreads();
        bf16x8 af[4], bfr[4];
        #pragma unroll
        for (int mt = 0; mt < 4; ++mt)
            af[mt] = *(const bf16x8*)&la[(wm * 64 + mt * 16 + col) * 32 + quad * 8];
        #pragma unroll
        for (int nt = 0; nt < 4; ++nt)
            bfr[nt] = *(const bf16x8*)&lb[(wn * 64 + nt * 16 + col) * 32 + quad * 8];
        #pragma unroll
        for (int mt = 0; mt < 4; ++mt)
            #pragma unroll
            for (int nt = 0; nt < 4; ++nt)
                acc[mt][nt] = __builtin_amdgcn_mfma_f32_16x16x32_bf16(
                    af[mt], bfr[nt], acc[mt][nt], 0, 0, 0);
    }
    float bia[4];
    #pragma unroll
    for (int nt = 0; nt < 4; ++nt) bia[nt] = bias[n0 + wn * 64 + nt * 16 + col];
    #pragma unroll
    for (int mt = 0; mt < 4; ++mt) {
        #pragma unroll
        for (int nt = 0; nt < 4; ++nt) {
            #pragma unroll
            for (int r = 0; r < 4; ++r) {
                int m = m0 + wm * 64 + mt * 16 + quad * 4 + r;
                int n = n0 + wn * 64 + nt * 16 + col;
                float v = (acc[mt][nt][r] + bia[nt]) * scale;
                if (MODE == 0) {
                    int b = m >> 11, l = m & 2047, h = n >> 6, d = n & 63;
                    ((bf16*)Out)[(((size_t)b * 16 + h) * 2048 + l) * 64 + d] = (bf16)v;
                } else {
                    int b = m >> 11, l = m & 2047, h = n >> 6, d = n & 63;
                    ((bf16*)Out)[(((size_t)b * 16 + h) * 64 + d) * 2048 + l] = (bf16)v;
                }
            }
        }
    }
}

// Q scaled by log2e (folded softmax base conversion); K,V unscaled; V -> V^T layout
__global__ __launch_bounds__(256) void qkv_kernel(
    const bf16* Xq, const bf16* Xk, const bf16* Xv,
    const bf16* Wq, const bf16* Wk, const bf16* Wv,
    const float* bq, const float* bk, const float* bv,
    bf16* Qh, bf16* Kh, bf16* Vt) {
    int y = blockIdx.y;
    int bm = blockIdx.x >> 3, bn = blockIdx.x & 7;
    if (y == 0)      gemm128_core<0>(Xq, Wq, bq, Qh, bm, bn, LOG2E);
    else if (y == 1) gemm128_core<0>(Xk, Wk, bk, Kh, bm, bn, 1.0f);
    else             gemm128_core<2>(Xv, Wv, bv, Vt, bm, bn, 1.0f);
}

// ---------------- 64x128 GEMM for output projection (fp32 out) ----------------
__global__ __launch_bounds__(256) void ogemm_kernel(const bf16* __restrict__ A,
                                                    const bf16* __restrict__ Wt,
                                                    const float* __restrict__ bias,
                                                    float* __restrict__ Out) {
    int bm = blockIdx.x >> 3, bn = blockIdx.x & 7;   // 64 x 8 tiles
    __shared__ __align__(16) bf16 la[64 * 32];
    __shared__ __align__(16) bf16 lb[128 * 32];
    int tid = threadIdx.x;
    int w = tid >> 6, lane = tid & 63;
    int quad = lane >> 4, col = lane & 15;
    int m0 = bm * 64, n0 = bn * 128;
    f32x4 acc[4][2];
    f32x4 z = {0.f, 0.f, 0.f, 0.f};
    #pragma unroll
    for (int i = 0; i < 4; ++i) { acc[i][0] = z; acc[i][1] = z; }
    int srow = lane >> 2;
    int skc = (lane & 3) * 8;
    for (int kt = 0; kt < 32; ++kt) {
        int kk = kt * 32;
        __syncthreads();
        g2l16(A + (size_t)(m0 + w * 16 + srow) * 1024 + kk + skc, &la[w * 512]);
        #pragma unroll
        for (int rr = 0; rr < 2; ++rr) {
            int ch = rr * 4 + w;
            g2l16(Wt + (size_t)(n0 + ch * 16 + srow) * 1024 + kk + skc, &lb[ch * 512]);
        }
        __syncthreads();
        bf16x8 af[4], bfr[2];
        #pragma unroll
        for (int mt = 0; mt < 4; ++mt)
            af[mt] = *(const bf16x8*)&la[(mt * 16 + col) * 32 + quad * 8];
        #pragma unroll
        for (int nt = 0; nt < 2; ++nt)
            bfr[nt] = *(const bf16x8*)&lb[(w * 32 + nt * 16 + col) * 32 + quad * 8];
        #pragma unroll
        for (int mt = 0; mt < 4; ++mt)
            #pragma unroll
            for (int nt = 0; nt < 2; ++nt)
                acc[mt][nt] = __builtin_amdgcn_mfma_f32_16x16x32_bf16(
                    af[mt], bfr[nt], acc[mt][nt], 0, 0, 0);
    }
    float bia[2];
    bia[0] = bias[n0 + w * 32 + col];
    bia[1] = bias[n0 + w * 32 + 16 + col];
    #pragma unroll
    for (int mt = 0; mt < 4; ++mt)
        #pragma unroll
        for (int nt = 0; nt < 2; ++nt)
            #pragma unroll
            for (int r = 0; r < 4; ++r)
                Out[(size_t)(m0 + mt * 16 + quad * 4 + r) * 1024 +
                    n0 + w * 32 + nt * 16 + col] = acc[mt][nt][r] + bia[nt];
}

// ---------------- flash attention, in-block KV split ----------------
// Block = 256 threads (4 waves), q-tile 64. Wave w: half = w>>1 (KV half),
// wq = w&1 (which 32 q-rows). Each half owns K/V LDS buffers (KV tile 32).
// Grid 32 bh x 32 qt = 1024 blocks x 4 waves = 16 waves/CU.
// Partial O and row-sums R combined exactly through LDS at the end.
// p = exp2(s) (log2e folded into Q projection). Mask: 1 cndmask per 64 elems
// via inverse_ballot of rmb words. Row sums: P x ones MFMA.
__global__ __launch_bounds__(256) void attn_kernel(const bf16* __restrict__ Qh,
                                                   const bf16* __restrict__ Kh,
                                                   const bf16* __restrict__ Vt,
                                                   const unsigned long long* __restrict__ rmb,
                                                   bf16* __restrict__ att) {
    int bh = blockIdx.x, qt = blockIdx.y;
    int b = bh >> 4, h = bh & 15;
    int q0 = qt * 64;
    // kv[half][0]=K tile 32x64 swizzled; kv[half][1]=V^T tile 64x32 swizzled.
    // Q (64x64) staged through kv[0..1][0] region first (contiguous 8KB).
    // After the loop kv is reused as f32 obuf[2][32][64] for the half-combine.
    __shared__ __align__(16) bf16 kv[2][2][32 * 64];   // 16 KB
    __shared__ __align__(16) bf16 ps[4][32 * 36];      // per-wave P, stride 36 (9 KB)
    int tid = threadIdx.x;
    int w = tid >> 6, lane = tid & 63;                 // w in 0..3
    int half = w >> 1, wq = w & 1;
    int quad = lane >> 4, col = lane & 15;
    int c7 = col & 7, c3 = col & 3;
    int sr = lane >> 3;              // K-stage: row-within-chunk (8 rows/chunk)
    int sg = (lane & 7) ^ sr;        // K-stage: swizzled d-group this lane fetches
    int vr = lane >> 2;              // V-stage: d-row-within-chunk (16 rows/chunk)
    int vg = (lane & 3) ^ (vr & 3);  // V-stage: swizzled k-group this lane fetches
    int swz0 = (quad ^ c7) * 8;      // k2=0 fragment offset (elements)
    int swz1 = ((4 + quad) ^ c7) * 8;

    // mask word base for this wave's first 16-row group (wave-uniform -> s_loads)
    int mofs = __builtin_amdgcn_readfirstlane((qt * 4 + wq * 2) * 512);

    // stage Q tile (64 rows, 8KB) through kv region; wave w stages chunks w*2..w*2+1
    bf16* qb = &kv[0][0][0];
    #pragma unroll
    for (int i = 0; i < 2; ++i) {
        int ch = w * 2 + i;
        g2l16(Qh + ((size_t)bh * 2048 + q0 + ch * 8 + sr) * 64 + sg * 8, qb + ch * 512);
    }
    __syncthreads();
    bf16x8 aq[2][2];
    #pragma unroll
    for (int mt = 0; mt < 2; ++mt) {
        aq[mt][0] = *(const bf16x8*)&qb[(wq * 32 + mt * 16 + col) * 64 + swz0];
        aq[mt][1] = *(const bf16x8*)&qb[(wq * 32 + mt * 16 + col) * 64 + swz1];
    }
    bf16x8 onesf;
    #pragma unroll
    for (int i = 0; i < 8; ++i) onesf[i] = (bf16)1.0f;

    f32x4 z = {0.f, 0.f, 0.f, 0.f};
    f32x4 O[2][4], R[2];
    #pragma unroll
    for (int mt = 0; mt < 2; ++mt) {
        R[mt] = z;
        #pragma unroll
        for (int i = 0; i < 4; ++i) O[mt][i] = z;
    }

    bf16* ksb = &kv[half][0][0];
    bf16* vsb = &kv[half][1][0];
    for (int it = 0; it < 32; ++it) {
        int kt = half * 32 + it;     // global 32-wide KV tile index (0..63)
        __syncthreads();   // (first iter: protects Q-frag reads before overwrite)
        // stage this half's K tile (32x64) and V^T tile (64x32); 2 waves share it
        #pragma unroll
        for (int i = 0; i < 2; ++i) {
            int ch = wq * 2 + i;
            g2l16(Kh + ((size_t)bh * 2048 + kt * 32 + ch * 8 + sr) * 64 + sg * 8,
                  ksb + ch * 512);
            g2l16(Vt + ((size_t)bh * 64 + ch * 16 + vr) * 2048 + kt * 32 + vg * 8,
                  vsb + ch * 512);
        }
        __syncthreads();

        // S = Q K^T : 32q x 32k per wave; each bk read feeds 2 MFMAs (mt)
        f32x4 s[2][2];
        #pragma unroll
        for (int nt = 0; nt < 2; ++nt) {
            s[0][nt] = z; s[1][nt] = z;
            bf16x8 bk0 = *(const bf16x8*)&ksb[(nt * 16 + col) * 64 + swz0];
            s[0][nt] = __builtin_amdgcn_mfma_f32_16x16x32_bf16(aq[0][0], bk0, s[0][nt], 0, 0, 0);
            s[1][nt] = __builtin_amdgcn_mfma_f32_16x16x32_bf16(aq[1][0], bk0, s[1][nt], 0, 0, 0);
            bf16x8 bk1 = *(const bf16x8*)&ksb[(nt * 16 + col) * 64 + swz1];
            s[0][nt] = __builtin_amdgcn_mfma_f32_16x16x32_bf16(aq[0][1], bk1, s[0][nt], 0, 0, 0);
            s[1][nt] = __builtin_amdgcn_mfma_f32_16x16x32_bf16(aq[1][1], bk1, s[1][nt], 0, 0, 0);
        }

        // p = exp2(s); zero masked lanes (1 cndmask per word); P -> per-wave LDS
        #pragma unroll
        for (int mt = 0; mt < 2; ++mt) {
            const unsigned long long* mw =
                rmb + mofs + mt * 512 + (kt >> 1) * 16 + (kt & 1) * 2;
            #pragma unroll
            for (int r = 0; r < 4; ++r) {
                #pragma unroll
                for (int nt = 0; nt < 2; ++nt) {
                    float p = __builtin_amdgcn_exp2f(s[mt][nt][r]);
                    if (lane_masked(mw[r * 4 + nt])) p = 0.0f;
                    ps[w][(mt * 16 + quad * 4 + r) * 36 + nt * 16 + col] = (bf16)p;
                }
            }
        }

        // O += P V ; R += P * ones (row sums) — wave-synchronous ps round-trip
        bf16x8 ap[2];
        ap[0] = *(const bf16x8*)&ps[w][(col) * 36 + quad * 8];
        ap[1] = *(const bf16x8*)&ps[w][(16 + col) * 36 + quad * 8];
        #pragma unroll
        for (int dt = 0; dt < 4; ++dt) {
            bf16x8 bv = *(const bf16x8*)&vsb[(dt * 16 + col) * 32 + (quad ^ c3) * 8];
            O[0][dt] = __builtin_amdgcn_mfma_f32_16x16x32_bf16(ap[0], bv, O[0][dt], 0, 0, 0);
            O[1][dt] = __builtin_amdgcn_mfma_f32_16x16x32_bf16(ap[1], bv, O[1][dt], 0, 0, 0);
        }
        R[0] = __builtin_amdgcn_mfma_f32_16x16x32_bf16(ap[0], onesf, R[0], 0, 0, 0);
        R[1] = __builtin_amdgcn_mfma_f32_16x16x32_bf16(ap[1], onesf, R[1], 0, 0, 0);
    }

    // ---- combine halves through LDS (exact: partial sums add) ----
    __syncthreads();                       // all waves done with kv reads
    float* obuf = (float*)&kv[0][0][0];    // [2][32][64] f32 = 16 KB
    float* rbuf = (float*)&ps[0][0];       // [2][32] f32 (ps dead)
    if (half == 1) {
        #pragma unroll
        for (int mt = 0; mt < 2; ++mt) {
            #pragma unroll
            for (int r = 0; r < 4; ++r) {
                int row = mt * 16 + quad * 4 + r;
                #pragma unroll
                for (int dt = 0; dt < 4; ++dt)
                    obuf[(size_t)wq * 2048 + row * 64 + dt * 16 + col] = O[mt][dt][r];
                if (col == 0) rbuf[wq * 32 + row] = R[mt][r];
            }
        }
    }
    __syncthreads();
    if (half == 0) {
        #pragma unroll
        for (int mt = 0; mt < 2; ++mt) {
            #pragma unroll
            for (int r = 0; r < 4; ++r) {
                int row = mt * 16 + quad * 4 + r;
                float rsv = R[mt][r] + rbuf[wq * 32 + row];
                float inv = (rsv > 0.f) ? 1.0f / rsv : 0.f;
                int qg = q0 + wq * 32 + row;
                #pragma unroll
                for (int dt = 0; dt < 4; ++dt) {
                    float ov = (O[mt][dt][r] +
                                obuf[(size_t)wq * 2048 + row * 64 + dt * 16 + col]) * inv;
                    att[((size_t)b * 2048 + qg) * 1024 + h * 64 + dt * 16 + col] = (bf16)ov;
                }
            }
        }
    }
}

extern "C" void kernel_launch(void* const* d_in, const int* in_sizes, int n_in,
                              void* d_out, int out_size, void* d_ws, size_t ws_size,
                              hipStream_t stream) {
    (void)in_sizes; (void)n_in; (void)out_size; (void)ws_size;
    const float* query = (const float*)d_in[0];
    const float* key_  = (const float*)d_in[1];
    const float* value = (const float*)d_in[2];
    const void*  mask  = d_in[3];
    const float* W_q = (const float*)d_in[4];
    const float* b_q = (const float*)d_in[5];
    const float* W_k = (const float*)d_in[6];
    const float* b_k = (const float*)d_in[7];
    const float* W_v = (const float*)d_in[8];
    const float* b_v = (const float*)d_in[9];
    const float* W_o = (const float*)d_in[10];
    const float* b_o = (const float*)d_in[11];

    char* ws = (char*)d_ws;
    bf16* Xq  = (bf16*)(ws + 0);
    bf16* Xk  = (bf16*)(ws + 8388608);
    bf16* Xv  = (bf16*)(ws + 16777216);
    bf16* Wtq = (bf16*)(ws + 25165824);
    bf16* Wtk = (bf16*)(ws + 27262976);
    bf16* Wtv = (bf16*)(ws + 29360128);
    bf16* Wto = (bf16*)(ws + 31457280);
    bf16* Qh  = (bf16*)(ws + 33554432);
    bf16* Kh  = (bf16*)(ws + 41943040);
    bf16* Vt  = (bf16*)(ws + 50331648);
    bf16* att = (bf16*)(ws + 58720256);
    unsigned long long* mb  = (unsigned long long*)(ws + 67108864);
    unsigned long long* rmb = (unsigned long long*)(ws + 67633152);
    int* flag = (int*)(ws + 68157440);

    hipMemsetAsync(flag, 0, 4, stream);
    mdetect_kernel<<<4096, 256, 0, stream>>>((const unsigned int*)mask, flag);
    mpack_kernel<<<16384, 256, 0, stream>>>(mask, mb, flag);
    rpack_kernel<<<1024, 256, 0, stream>>>(mb, rmb);

    cvt3_kernel<<<dim3(4096, 3), 256, 0, stream>>>(query, key_, value, Xq, Xk, Xv);
    wtrans_kernel<<<dim3(256, 4), 256, 0, stream>>>(W_q, W_k, W_v, W_o, Wtq, Wtk, Wtv, Wto);

    qkv_kernel<<<dim3(256, 3), 256, 0, stream>>>(Xq, Xk, Xv, Wtq, Wtk, Wtv,
                                                 b_q, b_k, b_v, Qh, Kh, Vt);
    attn_kernel<<<dim3(32, 32), 256, 0, stream>>>(Qh, Kh, Vt, rmb, att);
    ogemm_kernel<<<512, 256, 0, stream>>>(att, Wto, b_o, (float*)d_out);
}

// Round 2
// 290.567 us; speedup vs baseline: 1.1467x; 1.1467x over previous
//
#include <hip/hip_runtime.h>
#include <hip/hip_bf16.h>
#include <stdint.h>

// MultiHeadAttentionNoScale: B=2, L=2048, D=1024, H=16, dk=64.
// R8: revert R7's in-block KV split (regressed: halved work-per-barrier doubled
//     the relative stall cost). Back to R6 structure (q-tile 64, block 128,
//     grid 1024) + the 2-phase double-buffered K/V stage:
//       body(t): __syncthreads(); issue g2l16 tile t+1 -> OTHER buffer;
//                compute tile t from THIS buffer.
//     One barrier/iter; the vmcnt(0) drain at the barrier lands a full compute
//     phase after issue => prefetch latency hidden. Buffers are statically
//     distinct __shared__ symbols (loop unrolled x2) so compiler alias
//     analysis can't serialize ds_read(cur) against global_load_lds(next).
//     ps: stride 72 -> stride 64 + XOR swizzle ((row&7)<<3): conflict-free
//     reads (same swz0/swz1 as K/V frags), 2-way (free) writes, 8 KB.
//     LDS = 4*8KB (K/V dbuf) + 8KB ps = 40960 B => exactly 4 blocks/CU.

typedef __bf16 bf16;
typedef __bf16 bf16x8 __attribute__((ext_vector_type(8)));
typedef float f32x4 __attribute__((ext_vector_type(4)));

#define AS1 __attribute__((address_space(1)))
#define AS3 __attribute__((address_space(3)))

__device__ __forceinline__ void g2l16(const void* g, void* l) {
    // async global->LDS, 16B per lane; LDS dest = wave-uniform base + lane*16
    __builtin_amdgcn_global_load_lds((AS1 void*)g, (AS3 void*)l, 16, 0, 0);
}

// true iff this lane's bit is set in wave-uniform mask m
__device__ __forceinline__ bool lane_masked(unsigned long long m) {
#if __has_builtin(__builtin_amdgcn_inverse_ballot_w64)
    return __builtin_amdgcn_inverse_ballot_w64(m);
#else
    return (m >> (threadIdx.x & 63)) & 1ull;
#endif
}

#define LOG2E 1.44269504088896f

// ---------------- fp32 -> bf16 convert (3 tensors, one launch) ----------------
__global__ __launch_bounds__(256) void cvt3_kernel(const float* __restrict__ a0,
                                                   const float* __restrict__ a1,
                                                   const float* __restrict__ a2,
                                                   bf16* o0, bf16* o1, bf16* o2) {
    int y = blockIdx.y;
    const float* in = (y == 0) ? a0 : (y == 1) ? a1 : a2;
    bf16* out = (y == 0) ? o0 : (y == 1) ? o1 : o2;
    int idx = blockIdx.x * 256 + threadIdx.x;
    float4 v = ((const float4*)in)[idx];
    __align__(8) bf16 o[4];
    o[0] = (bf16)v.x; o[1] = (bf16)v.y; o[2] = (bf16)v.z; o[3] = (bf16)v.w;
    *(uint2*)(out + (size_t)idx * 4) = *(const uint2*)o;
}

// ---------------- mask representation detect (int32 / uint8 / fp32) ----------------
__global__ __launch_bounds__(256) void mdetect_kernel(const unsigned int* __restrict__ w,
                                                      int* __restrict__ flag) {
    int idx = blockIdx.x * 256 + threadIdx.x;
    unsigned v = w[idx];
    int f = 0;
    if (v == 0x3F800000u) f = 2;        // float 1.0 pattern -> fp32 mask
    else if (v > 1u) f = 1;             // bytes packed -> uint8 mask
    unsigned long long b1 = __ballot(f & 1);
    unsigned long long b2 = __ballot(f & 2);
    if ((threadIdx.x & 63) == 0) {
        int agg = (b1 ? 1 : 0) | (b2 ? 2 : 0);
        if (agg) atomicOr(flag, agg);
    }
}

// ---------------- mask -> bitmask mb[row][kword], bit=1 means masked ----------------
__global__ __launch_bounds__(256) void mpack_kernel(const void* __restrict__ mask,
                                                    unsigned long long* __restrict__ mb,
                                                    const int* __restrict__ flag) {
    int idx = blockIdx.x * 256 + threadIdx.x;
    int f = *flag;
    bool v;
    if (f & 2)      v = ((const float*)mask)[idx] != 0.0f;
    else if (f & 1) v = ((const unsigned char*)mask)[idx] != 0;
    else            v = ((const int*)mask)[idx] != 0;
    unsigned long long b = __ballot(v);
    if ((threadIdx.x & 63) == 0) mb[idx >> 6] = b;
}

// ---------------- mb -> rmb: lane-bit layout for attn's C-fragment ----------------
// word(task=qg*32+kt, r, nt): bit(lane) = mask[qg*16 + (lane>>4)*4 + r][kt*64 + nt*16 + (lane&15)]
__global__ __launch_bounds__(256) void rpack_kernel(const unsigned long long* __restrict__ mb,
                                                    unsigned long long* __restrict__ rmb) {
    int task = blockIdx.x * 4 + (threadIdx.x >> 6);   // 0..4095
    int qg = task >> 5, kt = task & 31;
    int lane = threadIdx.x & 63, quad = lane >> 4, col = lane & 15;
    #pragma unroll
    for (int r = 0; r < 4; ++r) {
        unsigned long long wrow = mb[(size_t)(qg * 16 + quad * 4 + r) * 32 + kt];
        #pragma unroll
        for (int nt = 0; nt < 4; ++nt) {
            unsigned long long b = __ballot(((wrow >> (nt * 16 + col)) & 1ull) != 0);
            if (lane == 0) rmb[(size_t)task * 16 + r * 4 + nt] = b;
        }
    }
}

// ---------------- W [k][n] fp32 -> Wt [n][k] bf16 (64x64 LDS tile transpose) ----------------
__global__ __launch_bounds__(256) void wtrans_kernel(const float* W0, const float* W1,
                                                     const float* W2, const float* W3,
                                                     bf16* T0, bf16* T1, bf16* T2, bf16* T3) {
    const float* W; bf16* T;
    int y = blockIdx.y;
    if (y == 0)      { W = W0; T = T0; }
    else if (y == 1) { W = W1; T = T1; }
    else if (y == 2) { W = W2; T = T2; }
    else             { W = W3; T = T3; }
    int tx = blockIdx.x & 15, ty = blockIdx.x >> 4;
    int n0 = tx * 64, k0 = ty * 64;
    __shared__ __align__(16) bf16 t[64 * 72];   // [k][n], +8 pad
    int tid = threadIdx.x;
    #pragma unroll
    for (int rr = 0; rr < 4; ++rr) {
        int idx = rr * 256 + tid;
        int r = idx >> 4, c4 = (idx & 15) * 4;
        float4 v = *(const float4*)(W + (size_t)(k0 + r) * 1024 + n0 + c4);
        __align__(8) bf16 o[4];
        o[0] = (bf16)v.x; o[1] = (bf16)v.y; o[2] = (bf16)v.z; o[3] = (bf16)v.w;
        *(uint2*)&t[r * 72 + c4] = *(const uint2*)o;
    }
    __syncthreads();
    #pragma unroll
    for (int rr = 0; rr < 2; ++rr) {
        int idx = rr * 256 + tid;
        int n = idx >> 3, kc = (idx & 7) * 8;
        __align__(16) bf16 o[8];
        #pragma unroll
        for (int j = 0; j < 8; ++j) o[j] = t[(kc + j) * 72 + n];
        *(uint4*)(T + (size_t)(n0 + n) * 1024 + k0 + kc) = *(const uint4*)o;
    }
}

// ---------------- 128x128 bt-GEMM core ----------------
// C[m,n] = (sum_k A[m,k]*Bt[n,k] + bias[n]) * scale
// MODE 0: bf16 head-layout [b][h][l][dk]; MODE 2: bf16 V^T [b][h][dk][l]
template <int MODE>
__device__ __forceinline__ void gemm128_core(const bf16* __restrict__ A,
                                             const bf16* __restrict__ Bt,
                                             const float* __restrict__ bias,
                                             void* __restrict__ Out, int bm, int bn,
                                             float scale) {
    __shared__ __align__(16) bf16 la[128 * 32];
    __shared__ __align__(16) bf16 lb[128 * 32];
    int tid = threadIdx.x;
    int w = tid >> 6, lane = tid & 63;
    int quad = lane >> 4, col = lane & 15;
    int wm = w >> 1, wn = w & 1;
    int m0 = bm * 128, n0 = bn * 128;
    f32x4 acc[4][4];
    f32x4 z = {0.f, 0.f, 0.f, 0.f};
    #pragma unroll
    for (int i = 0; i < 4; ++i)
        #pragma unroll
        for (int j = 0; j < 4; ++j) acc[i][j] = z;
    int srow = lane >> 2;
    int skc = (lane & 3) * 8;
    for (int kt = 0; kt < 32; ++kt) {
        int kk = kt * 32;
        __syncthreads();
        #pragma unroll
        for (int rr = 0; rr < 2; ++rr) {
            int ch = rr * 4 + w;
            int row = ch * 16 + srow;
            g2l16(A + (size_t)(m0 + row) * 1024 + kk + skc, &la[ch * 512]);
            g2l16(Bt + (size_t)(n0 + row) * 1024 + kk + skc, &lb[ch * 512]);
        }
        __syncthreads();
        bf16x8 af[4], bfr[4];
        #pragma unroll
        for (int mt = 0; mt < 4; ++mt)
            af[mt] = *(const bf16x8*)&la[(wm * 64 + mt * 16 + col) * 32 + quad * 8];
        #pragma unroll
        for (int nt = 0; nt < 4; ++nt)
            bfr[nt] = *(const bf16x8*)&lb[(wn * 64 + nt * 16 + col) * 32 + quad * 8];
        #pragma unroll
        for (int mt = 0; mt < 4; ++mt)
            #pragma unroll
            for (int nt = 0; nt < 4; ++nt)
                acc[mt][nt] = __builtin_amdgcn_mfma_f32_16x16x32_bf16(
                    af[mt], bfr[nt], acc[mt][nt], 0, 0, 0);
    }
    float bia[4];
    #pragma unroll
    for (int nt = 0; nt < 4; ++nt) bia[nt] = bias[n0 + wn * 64 + nt * 16 + col];
    #pragma unroll
    for (int mt = 0; mt < 4; ++mt) {
        #pragma unroll
        for (int nt = 0; nt < 4; ++nt) {
            #pragma unroll
            for (int r = 0; r < 4; ++r) {
                int m = m0 + wm * 64 + mt * 16 + quad * 4 + r;
                int n = n0 + wn * 64 + nt * 16 + col;
                float v = (acc[mt][nt][r] + bia[nt]) * scale;
                if (MODE == 0) {
                    int b = m >> 11, l = m & 2047, h = n >> 6, d = n & 63;
                    ((bf16*)Out)[(((size_t)b * 16 + h) * 2048 + l) * 64 + d] = (bf16)v;
                } else {
                    int b = m >> 11, l = m & 2047, h = n >> 6, d = n & 63;
                    ((bf16*)Out)[(((size_t)b * 16 + h) * 64 + d) * 2048 + l] = (bf16)v;
                }
            }
        }
    }
}

// Q scaled by log2e (folded softmax base conversion); K,V unscaled; V -> V^T layout
__global__ __launch_bounds__(256) void qkv_kernel(
    const bf16* Xq, const bf16* Xk, const bf16* Xv,
    const bf16* Wq, const bf16* Wk, const bf16* Wv,
    const float* bq, const float* bk, const float* bv,
    bf16* Qh, bf16* Kh, bf16* Vt) {
    int y = blockIdx.y;
    int bm = blockIdx.x >> 3, bn = blockIdx.x & 7;
    if (y == 0)      gemm128_core<0>(Xq, Wq, bq, Qh, bm, bn, LOG2E);
    else if (y == 1) gemm128_core<0>(Xk, Wk, bk, Kh, bm, bn, 1.0f);
    else             gemm128_core<2>(Xv, Wv, bv, Vt, bm, bn, 1.0f);
}

// ---------------- 64x128 GEMM for output projection (fp32 out) ----------------
__global__ __launch_bounds__(256) void ogemm_kernel(const bf16* __restrict__ A,
                                                    const bf16* __restrict__ Wt,
                                                    const float* __restrict__ bias,
                                                    float* __restrict__ Out) {
    int bm = blockIdx.x >> 3, bn = blockIdx.x & 7;   // 64 x 8 tiles
    __shared__ __align__(16) bf16 la[64 * 32];
    __shared__ __align__(16) bf16 lb[128 * 32];
    int tid = threadIdx.x;
    int w = tid >> 6, lane = tid & 63;
    int quad = lane >> 4, col = lane & 15;
    int m0 = bm * 64, n0 = bn * 128;
    f32x4 acc[4][2];
    f32x4 z = {0.f, 0.f, 0.f, 0.f};
    #pragma unroll
    for (int i = 0; i < 4; ++i) { acc[i][0] = z; acc[i][1] = z; }
    int srow = lane >> 2;
    int skc = (lane & 3) * 8;
    for (int kt = 0; kt < 32; ++kt) {
        int kk = kt * 32;
        __syncthreads();
        g2l16(A + (size_t)(m0 + w * 16 + srow) * 1024 + kk + skc, &la[w * 512]);
        #pragma unroll
        for (int rr = 0; rr < 2; ++rr) {
            int ch = rr * 4 + w;
            g2l16(Wt + (size_t)(n0 + ch * 16 + srow) * 1024 + kk + skc, &lb[ch * 512]);
        }
        __syncthreads();
        bf16x8 af[4], bfr[2];
        #pragma unroll
        for (int mt = 0; mt < 4; ++mt)
            af[mt] = *(const bf16x8*)&la[(mt * 16 + col) * 32 + quad * 8];
        #pragma unroll
        for (int nt = 0; nt < 2; ++nt)
            bfr[nt] = *(const bf16x8*)&lb[(w * 32 + nt * 16 + col) * 32 + quad * 8];
        #pragma unroll
        for (int mt = 0; mt < 4; ++mt)
            #pragma unroll
            for (int nt = 0; nt < 2; ++nt)
                acc[mt][nt] = __builtin_amdgcn_mfma_f32_16x16x32_bf16(
                    af[mt], bfr[nt], acc[mt][nt], 0, 0, 0);
    }
    float bia[2];
    bia[0] = bias[n0 + w * 32 + col];
    bia[1] = bias[n0 + w * 32 + 16 + col];
    #pragma unroll
    for (int mt = 0; mt < 4; ++mt)
        #pragma unroll
        for (int nt = 0; nt < 2; ++nt)
            #pragma unroll
            for (int r = 0; r < 4; ++r)
                Out[(size_t)(m0 + mt * 16 + quad * 4 + r) * 1024 +
                    n0 + w * 32 + nt * 16 + col] = acc[mt][nt][r] + bia[nt];
}

// ---------------- flash attention, 2-phase double-buffered K/V ----------------
// Block = 128 threads (2 waves), q-tile 64 (32 q-rows/wave). Grid 32x32 = 1024
// blocks = 4 blocks/CU (LDS 40960 B = 160/4 exactly). Per iteration:
//   __syncthreads(); issue 8 g2l16 (tile t+1) -> OTHER buffer; compute tile t.
// Static buffer symbols (kA/vA/kB/vB, loop unrolled x2) so alias analysis
// doesn't serialize ds_read(cur) against global_load_lds(next). The barrier's
// vmcnt(0) drain lands one full compute phase after issue -> latency hidden.
// ps: [2][32*64] bf16, XOR swizzle elem^((row&7)<<3): conflict-free b128 reads
// (offsets collapse to swz0/swz1), 2-way (free) b16 writes.
__global__ __launch_bounds__(128) void attn_kernel(const bf16* __restrict__ Qh,
                                                   const bf16* __restrict__ Kh,
                                                   const bf16* __restrict__ Vt,
                                                   const unsigned long long* __restrict__ rmb,
                                                   bf16* __restrict__ att) {
    int bh = blockIdx.x, qt = blockIdx.y;
    int b = bh >> 4, h = bh & 15;
    int q0 = qt * 64;
    __shared__ __align__(16) bf16 kA[64 * 64];
    __shared__ __align__(16) bf16 vA[64 * 64];
    __shared__ __align__(16) bf16 kB[64 * 64];
    __shared__ __align__(16) bf16 vB[64 * 64];
    __shared__ __align__(16) bf16 ps[2][32 * 64];  // XOR-swizzled P, per wave
    int tid = threadIdx.x;
    int w = tid >> 6, lane = tid & 63;
    int quad = lane >> 4, col = lane & 15;
    int c7 = col & 7;
    int sr = lane >> 3;              // staging: row-within-chunk (8 rows/chunk)
    int sg = (lane & 7) ^ sr;        // staging: swizzled d-group this lane fetches
    int swz0 = (quad ^ c7) * 8;      // k2=0 fragment offset (elements)
    int swz1 = ((4 + quad) ^ c7) * 8;

    // mask word base for this wave's first 16-row group (wave-uniform -> s_loads)
    int mofs = __builtin_amdgcn_readfirstlane((qt * 4 + w * 2) * 512);

    // stage Q tile (64 rows) through kA; wave w stages chunks w*4..w*4+3
    #pragma unroll
    for (int i = 0; i < 4; ++i) {
        int ch = w * 4 + i;
        g2l16(Qh + ((size_t)bh * 2048 + q0 + ch * 8 + sr) * 64 + sg * 8, &kA[ch * 512]);
    }
    __syncthreads();
    bf16x8 aq[2][2];
    #pragma unroll
    for (int mt = 0; mt < 2; ++mt) {
        aq[mt][0] = *(const bf16x8*)&kA[(w * 32 + mt * 16 + col) * 64 + swz0];
        aq[mt][1] = *(const bf16x8*)&kA[(w * 32 + mt * 16 + col) * 64 + swz1];
    }
    bf16x8 onesf;
    #pragma unroll
    for (int i = 0; i < 8; ++i) onesf[i] = (bf16)1.0f;

    f32x4 z = {0.f, 0.f, 0.f, 0.f};
    f32x4 O[2][4], R[2];
    #pragma unroll
    for (int mt = 0; mt < 2; ++mt) {
        R[mt] = z;
        #pragma unroll
        for (int i = 0; i < 4; ++i) O[mt][i] = z;
    }

    // all aq reads done (both waves) before tile-0 stage overwrites kA
    __syncthreads();
    // stage tile 0 into A (drained by the first body's top barrier)
    #pragma unroll
    for (int i = 0; i < 4; ++i) {
        int ch = w * 4 + i;
        int r = ch * 8 + sr;
        g2l16(Kh + ((size_t)bh * 2048 + r) * 64 + sg * 8, &kA[ch * 512]);
        g2l16(Vt + ((size_t)bh * 64 + r) * 2048 + sg * 8, &vA[ch * 512]);
    }

    auto body = [&](const bf16* RDk, const bf16* RDv, bf16* WRk, bf16* WRv, int t) {
        __syncthreads();   // tile-t loads drained (vmcnt0, issued a full phase ago); WAR protect
        // issue tile t+1 stages into the OTHER buffer (wraps harmlessly at t=31)
        int ktn = (t + 1) & 31;
        #pragma unroll
        for (int i = 0; i < 4; ++i) {
            int ch = w * 4 + i;
            int r = ch * 8 + sr;
            g2l16(Kh + ((size_t)bh * 2048 + ktn * 64 + r) * 64 + sg * 8, WRk + ch * 512);
            g2l16(Vt + ((size_t)bh * 64 + r) * 2048 + ktn * 64 + sg * 8, WRv + ch * 512);
        }

        // S = Q K^T : 32q x 64j per wave, each bk read feeds 2 MFMAs
        f32x4 s[2][4];
        #pragma unroll
        for (int nt = 0; nt < 4; ++nt) {
            s[0][nt] = z; s[1][nt] = z;
            bf16x8 bk0 = *(const bf16x8*)&RDk[(nt * 16 + col) * 64 + swz0];
            s[0][nt] = __builtin_amdgcn_mfma_f32_16x16x32_bf16(aq[0][0], bk0, s[0][nt], 0, 0, 0);
            s[1][nt] = __builtin_amdgcn_mfma_f32_16x16x32_bf16(aq[1][0], bk0, s[1][nt], 0, 0, 0);
            bf16x8 bk1 = *(const bf16x8*)&RDk[(nt * 16 + col) * 64 + swz1];
            s[0][nt] = __builtin_amdgcn_mfma_f32_16x16x32_bf16(aq[0][1], bk1, s[0][nt], 0, 0, 0);
            s[1][nt] = __builtin_amdgcn_mfma_f32_16x16x32_bf16(aq[1][1], bk1, s[1][nt], 0, 0, 0);
        }

        // p = exp2(s); zero masked lanes; P -> per-wave LDS (XOR-swizzled)
        #pragma unroll
        for (int mt = 0; mt < 2; ++mt) {
            const unsigned long long* mw = rmb + mofs + mt * 512 + t * 16;
            #pragma unroll
            for (int r = 0; r < 4; ++r) {
                int row = mt * 16 + quad * 4 + r;
                int xr = (quad * 4 + r) & 7;
                #pragma unroll
                for (int nt = 0; nt < 4; ++nt) {
                    float p = __builtin_amdgcn_exp2f(s[mt][nt][r]);
                    if (lane_masked(mw[r * 4 + nt])) p = 0.0f;
                    ps[w][row * 64 + ((nt * 16 + col) ^ (xr << 3))] = (bf16)p;
                }
            }
        }

        // O += P V ; R += P * ones — wave-synchronous ps round-trip
        bf16x8 ap[2][2];
        #pragma unroll
        for (int mt = 0; mt < 2; ++mt) {
            ap[mt][0] = *(const bf16x8*)&ps[w][(mt * 16 + col) * 64 + swz0];
            ap[mt][1] = *(const bf16x8*)&ps[w][(mt * 16 + col) * 64 + swz1];
        }
        #pragma unroll
        for (int dt = 0; dt < 4; ++dt) {
            bf16x8 bv0 = *(const bf16x8*)&RDv[(dt * 16 + col) * 64 + swz0];
            O[0][dt] = __builtin_amdgcn_mfma_f32_16x16x32_bf16(ap[0][0], bv0, O[0][dt], 0, 0, 0);
            O[1][dt] = __builtin_amdgcn_mfma_f32_16x16x32_bf16(ap[1][0], bv0, O[1][dt], 0, 0, 0);
            bf16x8 bv1 = *(const bf16x8*)&RDv[(dt * 16 + col) * 64 + swz1];
            O[0][dt] = __builtin_amdgcn_mfma_f32_16x16x32_bf16(ap[0][1], bv1, O[0][dt], 0, 0, 0);
            O[1][dt] = __builtin_amdgcn_mfma_f32_16x16x32_bf16(ap[1][1], bv1, O[1][dt], 0, 0, 0);
        }
        #pragma unroll
        for (int mt = 0; mt < 2; ++mt) {
            R[mt] = __builtin_amdgcn_mfma_f32_16x16x32_bf16(ap[mt][0], onesf, R[mt], 0, 0, 0);
            R[mt] = __builtin_amdgcn_mfma_f32_16x16x32_bf16(ap[mt][1], onesf, R[mt], 0, 0, 0);
        }
    };

    for (int t2 = 0; t2 < 16; ++t2) {
        body(kA, vA, kB, vB, t2 * 2);        // read A, prefetch tile 2t+1 -> B
        body(kB, vB, kA, vA, t2 * 2 + 1);    // read B, prefetch tile 2t+2 -> A
    }

    // epilogue: O/l, combined-head layout [b][l][h*64+d]; R holds row sums
    #pragma unroll
    for (int mt = 0; mt < 2; ++mt) {
        #pragma unroll
        for (int r = 0; r < 4; ++r) {
            float rsv = R[mt][r];
            float inv = (rsv > 0.f) ? 1.0f / rsv : 0.f;
            int qg = q0 + w * 32 + mt * 16 + quad * 4 + r;
            #pragma unroll
            for (int dt = 0; dt < 4; ++dt) {
                float ov = O[mt][dt][r] * inv;
                att[((size_t)b * 2048 + qg) * 1024 + h * 64 + dt * 16 + col] = (bf16)ov;
            }
        }
    }
}

extern "C" void kernel_launch(void* const* d_in, const int* in_sizes, int n_in,
                              void* d_out, int out_size, void* d_ws, size_t ws_size,
                              hipStream_t stream) {
    (void)in_sizes; (void)n_in; (void)out_size; (void)ws_size;
    const float* query = (const float*)d_in[0];
    const float* key_  = (const float*)d_in[1];
    const float* value = (const float*)d_in[2];
    const void*  mask  = d_in[3];
    const float* W_q = (const float*)d_in[4];
    const float* b_q = (const float*)d_in[5];
    const float* W_k = (const float*)d_in[6];
    const float* b_k = (const float*)d_in[7];
    const float* W_v = (const float*)d_in[8];
    const float* b_v = (const float*)d_in[9];
    const float* W_o = (const float*)d_in[10];
    const float* b_o = (const float*)d_in[11];

    char* ws = (char*)d_ws;
    bf16* Xq  = (bf16*)(ws + 0);
    bf16* Xk  = (bf16*)(ws + 8388608);
    bf16* Xv  = (bf16*)(ws + 16777216);
    bf16* Wtq = (bf16*)(ws + 25165824);
    bf16* Wtk = (bf16*)(ws + 27262976);
    bf16* Wtv = (bf16*)(ws + 29360128);
    bf16* Wto = (bf16*)(ws + 31457280);
    bf16* Qh  = (bf16*)(ws + 33554432);
    bf16* Kh  = (bf16*)(ws + 41943040);
    bf16* Vt  = (bf16*)(ws + 50331648);
    bf16* att = (bf16*)(ws + 58720256);
    unsigned long long* mb  = (unsigned long long*)(ws + 67108864);
    unsigned long long* rmb = (unsigned long long*)(ws + 67633152);
    int* flag = (int*)(ws + 68157440);

    hipMemsetAsync(flag, 0, 4, stream);
    mdetect_kernel<<<4096, 256, 0, stream>>>((const unsigned int*)mask, flag);
    mpack_kernel<<<16384, 256, 0, stream>>>(mask, mb, flag);
    rpack_kernel<<<1024, 256, 0, stream>>>(mb, rmb);

    cvt3_kernel<<<dim3(4096, 3), 256, 0, stream>>>(query, key_, value, Xq, Xk, Xv);
    wtrans_kernel<<<dim3(256, 4), 256, 0, stream>>>(W_q, W_k, W_v, W_o, Wtq, Wtk, Wtv, Wto);

    qkv_kernel<<<dim3(256, 3), 256, 0, stream>>>(Xq, Xk, Xv, Wtq, Wtk, Wtv,
                                                 b_q, b_k, b_v, Qh, Kh, Vt);
    attn_kernel<<<dim3(32, 32), 128, 0, stream>>>(Qh, Kh, Vt, rmb, att);
    ogemm_kernel<<<512, 256, 0, stream>>>(att, Wto, b_o, (float*)d_out);
}